// Round 5
// baseline (344.544 us; speedup 1.0000x reference)
//
#include <hip/hip_runtime.h>
#include <hip/hip_bf16.h>
#include <math.h>

#define BROWS 4096
#define NCOLS 8192
#define LLEN  256
#define EPSV  1e-8f
#define NEG_BIG -3.0e38f

__device__ __forceinline__ void lse_combine(float& m, float& s, float mo, float so) {
    float nm = fmaxf(m, mo);
    s = s * __expf(m - nm) + so * __expf(mo - nm);
    m = nm;
}

// One wave (64 threads) per row; lane l owns elements 4l..4l+3 in registers.
__global__ __launch_bounds__(64) void listmle_kernel(
    const float* __restrict__ logits,
    const int*   __restrict__ ids,
    const float* __restrict__ weights,
    float*       __restrict__ partial,
    unsigned*    __restrict__ counter,
    float*       __restrict__ out)
{
    __shared__ float s_g[LLEN];
    __shared__ float s_w[LLEN];
    __shared__ int   s_last;

    const int lane = threadIdx.x;          // 0..63
    const int b    = blockIdx.x;

    // ---- coalesced 16B loads; gather is 4 random loads in a 32KB row.
    const int base = b * LLEN + 4 * lane;
    const int4   id4 = *(const int4*)(ids + base);
    const float4 w4  = *(const float4*)(weights + base);
    const float* row = logits + (size_t)b * NCOLS;
    float g0 = row[id4.x], g1 = row[id4.y], g2 = row[id4.z], g3 = row[id4.w];

    // 32-bit keys: top-24 bits of weight (w in [0,1) => order-monotone),
    // low 8 bits = reversed element index (stable tie-break, descending sort).
    float wr[4] = {w4.x, w4.y, w4.z, w4.w};
    unsigned key[4];
    #pragma unroll
    for (int r = 0; r < 4; ++r)
        key[r] = (__float_as_uint(wr[r]) & 0xFFFFFF00u)
               | (unsigned)(LLEN - 1 - (4 * lane + r));

    // ---- full bitonic network on 256 elements, descending; no barriers.
    // j>=4 -> shfl_xor at lane distance j/4 (same register slot r);
    // j<4  -> in-register compare-exchange.  (g not needed: hides gather.)
    #pragma unroll
    for (int k = 2; k <= LLEN; k <<= 1) {
        #pragma unroll
        for (int j = k >> 1; j > 0; j >>= 1) {
            if (j >= 4) {
                const int jl = j >> 2;
                #pragma unroll
                for (int r = 0; r < 4; ++r) {
                    const int i = 4 * lane + r;
                    const bool keep_max = (((i & k) == 0) == ((i & j) == 0));
                    unsigned p  = __shfl_xor(key[r], jl);
                    unsigned mx = key[r] > p ? key[r] : p;
                    unsigned mn = key[r] > p ? p : key[r];
                    key[r] = keep_max ? mx : mn;
                }
            } else if (j == 2) {
                #pragma unroll
                for (int ra = 0; ra < 2; ++ra) {          // pairs (0,2),(1,3)
                    const int rb = ra + 2;
                    const int i  = 4 * lane + ra;          // (i&2)==0 for ra<2
                    const bool km = ((i & k) == 0);
                    unsigned a = key[ra], c = key[rb];
                    unsigned mx = a > c ? a : c, mn = a > c ? c : a;
                    key[ra] = km ? mx : mn;
                    key[rb] = km ? mn : mx;
                }
            } else {                                       // j == 1
                #pragma unroll
                for (int ra = 0; ra < 4; ra += 2) {        // pairs (0,1),(2,3)
                    const int rb = ra + 1;
                    const int i  = 4 * lane + ra;          // (i&1)==0 for even ra
                    const bool km = ((i & k) == 0);
                    unsigned a = key[ra], c = key[rb];
                    unsigned mx = a > c ? a : c, mn = a > c ? c : a;
                    key[ra] = km ? mx : mn;
                    key[rb] = km ? mn : mx;
                }
            }
        }
    }

    // ---- park (g,w) by original index; one barrier; permute via key payload.
    *(float4*)(s_g + 4 * lane) = make_float4(g0, g1, g2, g3);
    *(float4*)(s_w + 4 * lane) = make_float4(wr[0], wr[1], wr[2], wr[3]);
    __syncthreads();

    float og[4], ow[4];
    #pragma unroll
    for (int r = 0; r < 4; ++r) {
        const int pos = (LLEN - 1) - (int)(key[r] & 0xFFu);
        og[r] = s_g[pos];
        ow[r] = s_w[pos];
    }

    // ---- reverse logsumexp scan: in-register local suffixes + wave scan.
    float sm[4], ss[4];
    sm[3] = og[3]; ss[3] = 1.0f;
    #pragma unroll
    for (int r = 2; r >= 0; --r) {
        sm[r] = og[r]; ss[r] = 1.0f;
        lse_combine(sm[r], ss[r], sm[r + 1], ss[r + 1]);
    }
    float Am = sm[0], As = ss[0];                 // lane aggregate [4l..4l+3]
    #pragma unroll
    for (int off = 1; off < 64; off <<= 1) {      // inclusive reverse wave scan
        float pm = __shfl_down(Am, off);
        float ps = __shfl_down(As, off);
        if (lane + off < 64) lse_combine(Am, As, pm, ps);
    }
    float Em = __shfl_down(Am, 1);                // exclusive: lanes > l
    float Es = __shfl_down(As, 1);
    if (lane == 63) { Em = NEG_BIG; Es = 0.0f; }

    float t = 0.0f, ws = 0.0f;
    #pragma unroll
    for (int r = 0; r < 4; ++r) {
        float m = sm[r], s = ss[r];
        lse_combine(m, s, Em, Es);                // suffix over [4l+r .. 255]
        t  += ow[r] * ((m + __logf(s)) - og[r]);
        ws += ow[r];
    }
    #pragma unroll
    for (int o = 32; o > 0; o >>= 1) {
        t  += __shfl_down(t, o);
        ws += __shfl_down(ws, o);
    }

    // ---- fused finalize: last block to increment the ticket reduces partials.
    if (lane == 0) {
        partial[b] = t / fmaxf(ws, EPSV);
        __threadfence();
        unsigned old = atomicAdd(counter, 1u);
        s_last = (old == BROWS - 1) ? 1 : 0;
    }
    __syncthreads();
    if (s_last) {
        __threadfence();
        float v = 0.0f;
        #pragma unroll
        for (int i = 0; i < BROWS / 64; ++i)
            v += __hip_atomic_load(&partial[i * 64 + lane],
                                   __ATOMIC_RELAXED, __HIP_MEMORY_SCOPE_AGENT);
        #pragma unroll
        for (int o = 32; o > 0; o >>= 1) v += __shfl_down(v, o);
        if (lane == 0) out[0] = v * (1.0f / (float)BROWS);
    }
}

extern "C" void kernel_launch(void* const* d_in, const int* in_sizes, int n_in,
                              void* d_out, int out_size, void* d_ws, size_t ws_size,
                              hipStream_t stream) {
    const float* logits  = (const float*)d_in[0];
    const int*   ids     = (const int*)d_in[1];
    const float* weights = (const float*)d_in[2];
    float*    out     = (float*)d_out;
    float*    partial = (float*)d_ws;                 // 4096 floats
    unsigned* counter = (unsigned*)d_ws + BROWS;      // 1 uint, zeroed below

    hipMemsetAsync(counter, 0, sizeof(unsigned), stream);
    listmle_kernel<<<dim3(BROWS), dim3(64), 0, stream>>>(
        logits, ids, weights, partial, counter, out);
}